// Round 2
// baseline (194.234 us; speedup 1.0000x reference)
//
#include <hip/hip_runtime.h>

#define BLOCK 256
#define CHUNKS 8   // blocks per row: 8 x 256 rows = 2048 blocks = 8 blocks/CU

// out[b][j] = x[b][(j - s_b) mod T]
//
// Latency-bound fix: each thread handles ~T4/(CHUNKS*BLOCK) float4s in an
// unguarded, unrolled loop (MLP ~8 loads in flight per wave) instead of one.
// Misalignment a = (-s) & 3 is uniform per row; the select is hoisted out of
// the loop via template dispatch (no divergence, no runtime-indexed arrays).
// All loads/stores are 16B-aligned dwordx4; the B-chunk overlaps the next
// lane's A-chunk so it is an L1 hit (HBM read traffic stays 1x).

template <int ASEL>
__device__ __forceinline__ void roll_chunk(const float* __restrict__ xr,
                                           float* __restrict__ outr,
                                           int T, int sa, int v0, int vend) {
    const int nfull = (vend - v0) / BLOCK;  // iterations valid for ALL lanes
    int v = v0 + (int)threadIdx.x;

#pragma unroll 4
    for (int k = 0; k < nfull; ++k, v += BLOCK) {
        const int j = v << 2;
        int i4 = j - sa;               // j in [0,T), sa in [0,T) -> i4 in (-T,T)
        if (i4 < 0) i4 += T;           // 16B-aligned, <= T-4: never overruns row
        const float4 A = *reinterpret_cast<const float4*>(xr + i4);
        float4 r;
        if constexpr (ASEL == 0) {
            r = A;
        } else {
            int i4b = i4 + 4;
            if (i4b >= T) i4b -= T;
            const float4 Bv = *reinterpret_cast<const float4*>(xr + i4b);
            if constexpr (ASEL == 1)      r = make_float4(A.y, A.z, A.w, Bv.x);
            else if constexpr (ASEL == 2) r = make_float4(A.z, A.w, Bv.x, Bv.y);
            else                          r = make_float4(A.w, Bv.x, Bv.y, Bv.z);
        }
        *reinterpret_cast<float4*>(outr + j) = r;
    }

    // tail: partial last iteration
    if (v < vend) {
        const int j = v << 2;
        int i4 = j - sa;
        if (i4 < 0) i4 += T;
        const float4 A = *reinterpret_cast<const float4*>(xr + i4);
        float4 r;
        if constexpr (ASEL == 0) {
            r = A;
        } else {
            int i4b = i4 + 4;
            if (i4b >= T) i4b -= T;
            const float4 Bv = *reinterpret_cast<const float4*>(xr + i4b);
            if constexpr (ASEL == 1)      r = make_float4(A.y, A.z, A.w, Bv.x);
            else if constexpr (ASEL == 2) r = make_float4(A.z, A.w, Bv.x, Bv.y);
            else                          r = make_float4(A.w, Bv.x, Bv.y, Bv.z);
        }
        *reinterpret_cast<float4*>(outr + j) = r;
    }
}

__global__ __launch_bounds__(BLOCK)
void roll_rows_chunked(const float* __restrict__ x,
                       const int* __restrict__ shifts,
                       float* __restrict__ out,
                       int T, int T4) {
    const int b = blockIdx.y;
    const float* __restrict__ xr = x + (size_t)b * (size_t)T;
    float* __restrict__ outr = out + (size_t)b * (size_t)T;

    int s = shifts[b] % T;             // shifts in [0,1000); defensive
    if (s < 0) s += T;
    const int a = (-s) & 3;            // per-row-uniform misalignment (floats)
    int sa = s + a;                    // i4 = (j - sa) mod T, 16B-aligned
    if (sa >= T) sa -= T;

    const int cnt = (T4 + CHUNKS - 1) / CHUNKS;
    const int v0 = blockIdx.x * cnt;
    const int vend = min(v0 + cnt, T4);
    if (v0 >= vend) return;

    switch (a) {  // wave-uniform
        case 0:  roll_chunk<0>(xr, outr, T, sa, v0, vend); break;
        case 1:  roll_chunk<1>(xr, outr, T, sa, v0, vend); break;
        case 2:  roll_chunk<2>(xr, outr, T, sa, v0, vend); break;
        default: roll_chunk<3>(xr, outr, T, sa, v0, vend); break;
    }
}

// Generic scalar fallback (T not divisible by 4).
__global__ void roll_rows_scalar(const float* __restrict__ x,
                                 const int* __restrict__ shifts,
                                 float* __restrict__ out,
                                 int T) {
    const int b = blockIdx.y;
    const int j = blockIdx.x * blockDim.x + threadIdx.x;
    if (j >= T) return;
    int s = shifts[b] % T;
    if (s < 0) s += T;
    int i = j - s;
    if (i < 0) i += T;
    out[(size_t)b * T + j] = x[(size_t)b * T + i];
}

extern "C" void kernel_launch(void* const* d_in, const int* in_sizes, int n_in,
                              void* d_out, int out_size, void* d_ws, size_t ws_size,
                              hipStream_t stream) {
    const float* x = (const float*)d_in[0];
    const int* shifts = (const int*)d_in[1];
    float* out = (float*)d_out;

    const int B = in_sizes[1];
    const int T = in_sizes[0] / B;

    if ((T & 3) == 0) {
        const int T4 = T / 4;
        dim3 block(BLOCK);
        dim3 grid(CHUNKS, B);
        roll_rows_chunked<<<grid, block, 0, stream>>>(x, shifts, out, T, T4);
    } else {
        dim3 block(256);
        dim3 grid((T + 255) / 256, B);
        roll_rows_scalar<<<grid, block, 0, stream>>>(x, shifts, out, T);
    }
}

// Round 4
// 177.640 us; speedup vs baseline: 1.0934x; 1.0934x over previous
//
#include <hip/hip_runtime.h>

#define BLOCK 256
#define VPT 2   // float4s per thread, straight-line (no loop)

typedef float f32x4 __attribute__((ext_vector_type(4)));

// out[b][j] = x[b][(j - s_b) mod T]
//
// Structure: flat one-shot waves (round-1 winner), 2 independent float4s per
// thread for MLP, aligned reads via per-row-uniform realignment (a = (-s)&3,
// wave-uniform switch -> no divergence), and NON-TEMPORAL stores so the
// 100 MB write stream does not write-allocate in L2/L3 and evict the x lines
// the read stream needs (FETCH_SIZE showed ~half of x already falling out).

template <int ASEL>
__device__ __forceinline__ f32x4 fetch4(const float* __restrict__ xr, int T, int i4) {
    const f32x4 A = *reinterpret_cast<const f32x4*>(xr + i4);
    if constexpr (ASEL == 0) {
        return A;
    } else {
        int i4b = i4 + 4;
        if (i4b >= T) i4b -= T;
        const f32x4 Bv = *reinterpret_cast<const f32x4*>(xr + i4b);
        f32x4 r;
        if constexpr (ASEL == 1)      { r.x = A.y; r.y = A.z; r.z = A.w; r.w = Bv.x; }
        else if constexpr (ASEL == 2) { r.x = A.z; r.y = A.w; r.z = Bv.x; r.w = Bv.y; }
        else                          { r.x = A.w; r.y = Bv.x; r.z = Bv.y; r.w = Bv.z; }
        return r;
    }
}

template <int ASEL>
__device__ __forceinline__ void do_pair(const float* __restrict__ xr,
                                        float* __restrict__ outr,
                                        int T, int T4, int sa,
                                        int v1, int v2) {
    // Independent straight-line pair: both loads issue before either store.
    if (v1 < T4) {
        const int j1 = v1 << 2;
        int i1 = j1 - sa; if (i1 < 0) i1 += T;     // stays 16B-aligned (sa%4==0, T%4==0)
        const f32x4 r1 = fetch4<ASEL>(xr, T, i1);
        if (v2 < T4) {
            const int j2 = v2 << 2;
            int i2 = j2 - sa; if (i2 < 0) i2 += T;
            const f32x4 r2 = fetch4<ASEL>(xr, T, i2);
            __builtin_nontemporal_store(r2, reinterpret_cast<f32x4*>(outr + j2));
        }
        __builtin_nontemporal_store(r1, reinterpret_cast<f32x4*>(outr + j1));
    }
}

__global__ __launch_bounds__(BLOCK)
void roll_rows_nt(const float* __restrict__ x,
                  const int* __restrict__ shifts,
                  float* __restrict__ out,
                  int T, int T4) {
    const int b = blockIdx.y;
    const float* __restrict__ xr = x + (size_t)b * (size_t)T;
    float* __restrict__ outr = out + (size_t)b * (size_t)T;

    int s = shifts[b] % T;              // shifts in [0,1000); defensive
    if (s < 0) s += T;
    const int a = (-s) & 3;             // per-row-uniform misalignment (floats)
    int sa = s + a;                     // multiple of 4; i4 = (4v - sa) mod T
    if (sa >= T) sa -= T;

    const int v1 = blockIdx.x * (BLOCK * VPT) + (int)threadIdx.x;
    const int v2 = v1 + BLOCK;

    switch (a) {  // wave-uniform
        case 0:  do_pair<0>(xr, outr, T, T4, sa, v1, v2); break;
        case 1:  do_pair<1>(xr, outr, T, T4, sa, v1, v2); break;
        case 2:  do_pair<2>(xr, outr, T, T4, sa, v1, v2); break;
        default: do_pair<3>(xr, outr, T, T4, sa, v1, v2); break;
    }
}

// Generic scalar fallback (T not divisible by 4).
__global__ void roll_rows_scalar(const float* __restrict__ x,
                                 const int* __restrict__ shifts,
                                 float* __restrict__ out,
                                 int T) {
    const int b = blockIdx.y;
    const int j = blockIdx.x * blockDim.x + threadIdx.x;
    if (j >= T) return;
    int s = shifts[b] % T;
    if (s < 0) s += T;
    int i = j - s;
    if (i < 0) i += T;
    out[(size_t)b * T + j] = x[(size_t)b * T + i];
}

extern "C" void kernel_launch(void* const* d_in, const int* in_sizes, int n_in,
                              void* d_out, int out_size, void* d_ws, size_t ws_size,
                              hipStream_t stream) {
    const float* x = (const float*)d_in[0];
    const int* shifts = (const int*)d_in[1];
    float* out = (float*)d_out;

    const int B = in_sizes[1];
    const int T = in_sizes[0] / B;

    if ((T & 3) == 0) {
        const int T4 = T / 4;
        dim3 block(BLOCK);
        dim3 grid((T4 + BLOCK * VPT - 1) / (BLOCK * VPT), B);
        roll_rows_nt<<<grid, block, 0, stream>>>(x, shifts, out, T, T4);
    } else {
        dim3 block(256);
        dim3 grid((T + 255) / 256, B);
        roll_rows_scalar<<<grid, block, 0, stream>>>(x, shifts, out, T);
    }
}